// Round 2
// baseline (1653.253 us; speedup 1.0000x reference)
//
#include <hip/hip_runtime.h>
#include <hip/hip_bf16.h>

// NeuronConvNet, Round 6: drop LDS staging entirely (Common-mistake #7).
// Per-block working sets (8-22KB) are L1/L2-resident; LDS staging + 2
// barriers + 4x ds_read_b32 per MFMA were the bottleneck, not HBM.
//  - A fragments: direct coalesced 16B/lane loads from prep_A's
//    fragment-major layout (L2-hot, shared by all blocks of a group).
//  - B fragments: 8 consecutive t-values per lane. bf16 rows have an
//    odd t-origin -> load 5 dwords at even base gt0-1 + v_alignbit
//    funnel shift. fp32 rows are 4B-aligned -> 2x dwordx4 + cvt.
//  - Edge tiles (0, 15) take a block-uniform scalar slow path.
//  - LDS = s_c output shuffle only (4.2KB); one barrier per block.

#define T_LEN 4096
#define KK    15
#define TW    256            // output t-tile per block (16 tiles)
#define SCP   264            // s_c row stride (shorts)

typedef __attribute__((ext_vector_type(8))) short    short8;
typedef __attribute__((ext_vector_type(4))) short    short4_t;
typedef __attribute__((ext_vector_type(4))) float    f32x4;
typedef __attribute__((ext_vector_type(4))) unsigned uint4_t;

static __device__ __forceinline__ short f2bf(float f) {
    union { __hip_bfloat16 b; short s; } u; u.b = __float2bfloat16(f); return u.s;
}
static __device__ __forceinline__ float bf2f(short s) {
    union { unsigned u; float f; } u; u.u = ((unsigned)(unsigned short)s) << 16; return u.f;
}

#define MODE_F32   0
#define MODE_BF16  1
#define MODE_SPLIT 2

// ---- Aprep layout: per layer, [g][j][lane][8] bf16, A[m=lane&15][kap] ----
// kap = j*32 + (lane>>4)*8 + e ; A[m][ic*16+kp] = W[g*8+(m&7)][ic][kp-(m>>3)]
#define AP_LEAF  0
#define AP_INT0  327680   // + 64*16*320
#define AP_BR    458752   // + 32*16*256
#define AP_INT1  589824
#define AP_INT2  655360
#define AP_INT3  688128
#define AP_INT4  704512
#define AP_TOTAL 712704

__global__ __launch_bounds__(256) void prep_A(
    const float* __restrict__ W0, const float* __restrict__ W1,
    const float* __restrict__ W2, const float* __restrict__ W3,
    const float* __restrict__ W4, const float* __restrict__ W5,
    const float* __restrict__ W6, short* __restrict__ Ap)
{
    const int idx = blockIdx.x * 256 + threadIdx.x;
    if (idx >= AP_TOTAL) return;
    const float* W; int ipg, base;
    if      (idx < AP_INT0) { W = W0; ipg = 20; base = AP_LEAF; }
    else if (idx < AP_BR)   { W = W1; ipg = 16; base = AP_INT0; }
    else if (idx < AP_INT1) { W = W2; ipg = 16; base = AP_BR;   }
    else if (idx < AP_INT2) { W = W3; ipg = 16; base = AP_INT1; }
    else if (idx < AP_INT3) { W = W4; ipg = 16; base = AP_INT2; }
    else if (idx < AP_INT4) { W = W5; ipg = 16; base = AP_INT3; }
    else                    { W = W6; ipg = 16; base = AP_INT4; }
    const int local = idx - base;
    const int e    = local & 7;
    const int fl   = local >> 3;
    const int lane = fl & 63;
    const int fj   = fl >> 6;           // g*NM + j
    int g, j;
    if (ipg == 20) { g = fj / 10; j = fj - g * 10; }
    else           { g = fj >> 3; j = fj & 7; }
    const int m   = lane & 15;
    const int kap = j * 32 + (lane >> 4) * 8 + e;
    const int ic  = kap >> 4, kp = kap & 15;
    const int k   = kp - (m >> 3);
    float v = 0.f;
    if (k >= 0 && k < KK)
        v = W[((size_t)(g * 8 + (m & 7)) * ipg + ic) * KK + k];
    Ap[idx] = f2bf(v);
}

// B-fragment loaders: 8 consecutive bf16 values at t = gt0 .. gt0+7
// (zero outside [0,T_LEN)).  gt0 is ODD -> bf16 path uses 5 dwords at
// even base E=gt0-1 + alignbit;  fp32 path is naturally 4B-aligned.
template <bool INTERIOR>
static __device__ __forceinline__ short8 load_b_bf16(const short* __restrict__ row, int gt0)
{
    unsigned d[5];
    const int E = gt0 - 1;
    if constexpr (INTERIOR) {
        uint4_t dd;
        __builtin_memcpy(&dd, row + E, 16);       // 4B-aligned dwordx4
        d[0] = dd[0]; d[1] = dd[1]; d[2] = dd[2]; d[3] = dd[3];
        __builtin_memcpy(&d[4], row + E + 8, 4);
    } else {
#pragma unroll
        for (int i = 0; i < 5; ++i) {
            const int ta = E + 2 * i, tb = ta + 1;
            const unsigned lo = (ta >= 0 && ta < T_LEN) ? (unsigned short)row[ta] : 0u;
            const unsigned hi = (tb >= 0 && tb < T_LEN) ? (unsigned short)row[tb] : 0u;
            d[i] = lo | (hi << 16);
        }
    }
    union { unsigned u[4]; short8 v; } r;
#pragma unroll
    for (int i = 0; i < 4; ++i)
        r.u[i] = __builtin_amdgcn_alignbit(d[i + 1], d[i], 16);
    return r.v;
}

template <bool INTERIOR>
static __device__ __forceinline__ short8 load_b_f32(const float* __restrict__ row, int gt0)
{
    float f[8];
    if constexpr (INTERIOR) {
        f32x4 a, b;
        __builtin_memcpy(&a, row + gt0, 16);      // 4B-aligned dwordx4
        __builtin_memcpy(&b, row + gt0 + 4, 16);
        f[0] = a[0]; f[1] = a[1]; f[2] = a[2]; f[3] = a[3];
        f[4] = b[0]; f[5] = b[1]; f[6] = b[2]; f[7] = b[3];
    } else {
#pragma unroll
        for (int i = 0; i < 8; ++i) {
            const int t = gt0 + i;
            f[i] = (t >= 0 && t < T_LEN) ? row[t] : 0.f;
        }
    }
    short8 r;
#pragma unroll
    for (int i = 0; i < 8; ++i) r[i] = f2bf(f[i]);
    return r;
}

template <int IPG, int MODE, bool INTERIOR>
static __device__ __forceinline__ void gconv_body(
    const void* __restrict__ inA_, int cinA,
    const float* __restrict__ inX, int cinX, int xbase,
    const short* __restrict__ Ap,
    const float* __restrict__ bias,
    short* __restrict__ s_c,
    int tile, int g, int b, int tid)
{
    constexpr int KD = IPG * 16;   // padded K dim (320 or 256)
    constexpr int NM = KD / 32;    // MFMAs per output tile (10 or 8)

    const int l  = tid & 63;          // lane
    const int wv = tid >> 6;          // wave 0..3 (uniform)
    const int n  = l & 15, q = l >> 4;

    // ---- A fragments: coalesced 16B/lane from fragment-major global ----
    short8 fa[NM];
    {
        const short* Ag = Ap + (size_t)g * (16 * KD);
#pragma unroll
        for (int j = 0; j < NM; ++j)
            fa[j] = *(const short8*)&Ag[(j * 64 + l) * 8];
    }

    float bv[4];
#pragma unroll
    for (int r = 0; r < 4; ++r) bv[r] = bias[g * 8 + ((q * 4 + r) & 7)];

    for (int c = 0; c < 2; ++c) {
        const int co  = (wv * 2 + c) * 32;                 // chunk t-offset
        const int gt0 = tile * TW - 7 + co + 2 * n + 8 * (q & 1);  // odd
        f32x4 acc = {bv[0], bv[1], bv[2], bv[3]};
#pragma unroll
        for (int j = 0; j < NM; ++j) {
            const int ic = j * 2 + (q >> 1);
            short8 bf;
            if constexpr (MODE == MODE_F32) {
                const float* row = (const float*)inA_ +
                    ((size_t)b * cinA + g * IPG + ic) * T_LEN;
                bf = load_b_f32<INTERIOR>(row, gt0);
            } else if constexpr (MODE == MODE_BF16) {
                const short* row = (const short*)inA_ +
                    ((size_t)b * cinA + g * IPG + ic) * T_LEN;
                bf = load_b_bf16<INTERIOR>(row, gt0);
            } else {          // MODE_SPLIT: j<NM/2 -> bf16 bufB, else fp32 x
                if (j < NM / 2) {
                    const short* row = (const short*)inA_ +
                        ((size_t)b * cinA + g * 8 + ic) * T_LEN;
                    bf = load_b_bf16<INTERIOR>(row, gt0);
                } else {
                    const float* row = inX +
                        ((size_t)b * cinX + xbase + g * 8 + (ic - 8)) * T_LEN;
                    bf = load_b_f32<INTERIOR>(row, gt0);
                }
            }
            acc = __builtin_amdgcn_mfma_f32_16x16x32_bf16(fa[j], bf, acc, 0, 0, 0);
        }
        // leaky-relu + scatter into linear [oc][t] staging (bf16)
#pragma unroll
        for (int r = 0; r < 4; ++r) {
            float vv = acc[r];
            vv = vv > 0.f ? vv : 0.01f * vv;
            const int m = q * 4 + r, oc = m & 7, s = m >> 3;
            s_c[oc * SCP + co + 2 * n + s] = f2bf(vv);
        }
    }
}

template <int IPG, int MODE>
__global__ __launch_bounds__(256) void gconv_mfma(
    const void*  __restrict__ inA_, int cinA,
    const float* __restrict__ inX,  int cinX, int xbase,
    const short* __restrict__ Ap,      // layer base pre-added
    const float* __restrict__ bias,
    short* __restrict__ out, int Cout)
{
    __shared__ __align__(16) short s_c[8 * SCP];

    const int tile = blockIdx.x, g = blockIdx.y, b = blockIdx.z;
    const int tid  = threadIdx.x;

    if (tile > 0 && tile < (int)gridDim.x - 1)
        gconv_body<IPG, MODE, true >(inA_, cinA, inX, cinX, xbase, Ap, bias,
                                     s_c, tile, g, b, tid);
    else
        gconv_body<IPG, MODE, false>(inA_, cinA, inX, cinX, xbase, Ap, bias,
                                     s_c, tile, g, b, tid);

    __syncthreads();

    // ---- coalesced bf16 store: 8 rows x 256 cols, 16B per thread ----
    {
        const int oc = tid >> 5, col = (tid & 31) * 8;
        const short8 vvv = *(const short8*)&s_c[oc * SCP + col];
        *(short8*)(out + ((size_t)b * Cout + g * 8 + oc) * T_LEN + tile * TW + col) = vvv;
    }
}

// 1x1 conv over 16 bf16 channels -> fp32 out, vectorized x4
__global__ __launch_bounds__(256) void root_kernel(
    const short* __restrict__ h,
    const float* __restrict__ W,
    const float* __restrict__ bias,
    float* __restrict__ out)
{
    const int idx = blockIdx.x * 256 + threadIdx.x;   // (b*T + t)/4
    const int b  = idx >> 10;
    const int t4 = (idx & 1023) * 4;
    const float bb = bias[0];
    float a0 = bb, a1 = bb, a2 = bb, a3 = bb;
#pragma unroll
    for (int ic = 0; ic < 16; ++ic) {
        const short4_t v = *(const short4_t*)&h[((size_t)b * 16 + ic) * T_LEN + t4];
        const float w = W[ic];
        a0 += w * bf2f(v[0]); a1 += w * bf2f(v[1]);
        a2 += w * bf2f(v[2]); a3 += w * bf2f(v[3]);
    }
    f32x4 o = {a0, a1, a2, a3};
    *(f32x4*)&out[(size_t)idx * 4] = o;
}

extern "C" void kernel_launch(void* const* d_in, const int* in_sizes, int n_in,
                              void* d_out, int out_size, void* d_ws, size_t ws_size,
                              hipStream_t stream)
{
    const float* x      = (const float*)d_in[0];
    const float* W_leaf = (const float*)d_in[1];
    const float* b_leaf = (const float*)d_in[2];
    const float* W_int0 = (const float*)d_in[3];
    const float* b_int0 = (const float*)d_in[4];
    const float* W_br   = (const float*)d_in[5];
    const float* b_br   = (const float*)d_in[6];
    const float* W_int1 = (const float*)d_in[7];
    const float* b_int1 = (const float*)d_in[8];
    const float* W_int2 = (const float*)d_in[9];
    const float* b_int2 = (const float*)d_in[10];
    const float* W_int3 = (const float*)d_in[11];
    const float* b_int3 = (const float*)d_in[12];
    const float* W_int4 = (const float*)d_in[13];
    const float* b_int4 = (const float*)d_in[14];
    const float* W_root = (const float*)d_in[15];
    const float* b_root = (const float*)d_in[16];

    // ws: bufA (67.1MB) | bufB (33.6MB) | Aprep (1.43MB) = 102.1MB total
    short* bufA = (short*)d_ws;
    short* bufB = bufA + (size_t)16 * 512 * 4096;
    short* Ap   = bufB + (size_t)16 * 256 * 4096;

    const int tiles = T_LEN / TW;  // 16
    const dim3 blk(256);

    prep_A<<<dim3(AP_TOTAL / 256), blk, 0, stream>>>(
        W_leaf, W_int0, W_br, W_int1, W_int2, W_int3, W_int4, Ap);

    // leaf: x fp32 (ch=g*20+r) -> bufA (512 ch bf16)
    gconv_mfma<20, MODE_F32><<<dim3(tiles, 64, 16), blk, 0, stream>>>(
        x, 1536, nullptr, 0, 0, Ap + AP_LEAF, b_leaf, bufA, 512);
    // int0: bufA (512) -> bufB (256)
    gconv_mfma<16, MODE_BF16><<<dim3(tiles, 32, 16), blk, 0, stream>>>(
        bufA, 512, nullptr, 0, 0, Ap + AP_INT0, b_int0, bufB, 256);
    // br: [bufB (256) | x ch1280..1535 fp32] -> bufA (256)
    gconv_mfma<16, MODE_SPLIT><<<dim3(tiles, 32, 16), blk, 0, stream>>>(
        bufB, 256, x, 1536, 1280, Ap + AP_BR, b_br, bufA, 256);
    // int1: bufA (256) -> bufB (128)
    gconv_mfma<16, MODE_BF16><<<dim3(tiles, 16, 16), blk, 0, stream>>>(
        bufA, 256, nullptr, 0, 0, Ap + AP_INT1, b_int1, bufB, 128);
    // int2: bufB (128) -> bufA (64)
    gconv_mfma<16, MODE_BF16><<<dim3(tiles, 8, 16), blk, 0, stream>>>(
        bufB, 128, nullptr, 0, 0, Ap + AP_INT2, b_int2, bufA, 64);
    // int3: bufA (64) -> bufB (32)
    gconv_mfma<16, MODE_BF16><<<dim3(tiles, 4, 16), blk, 0, stream>>>(
        bufA, 64, nullptr, 0, 0, Ap + AP_INT3, b_int3, bufB, 32);
    // int4: bufB (32) -> bufA (16)
    gconv_mfma<16, MODE_BF16><<<dim3(tiles, 2, 16), blk, 0, stream>>>(
        bufB, 32, nullptr, 0, 0, Ap + AP_INT4, b_int4, bufA, 16);
    // root: bufA (16 ch bf16) -> d_out fp32
    root_kernel<<<dim3((16 * T_LEN / 4) / 256), blk, 0, stream>>>(
        bufA, W_root, b_root, (float*)d_out);
}

// Round 4
// 650.882 us; speedup vs baseline: 2.5400x; 2.5400x over previous
//
#include <hip/hip_runtime.h>
#include <hip/hip_bf16.h>

// NeuronConvNet, Round 8: R5 core (verified 661us) + fused tail.
//  - R7 post-mortem: 32x32x16 with 4 shifts needs 18 K-slots > 16 ->
//    taps dropped (absmax 7e-3). 16x16x32 with 2 shifts is the exact
//    fit (15 taps + 1 shift = 16). Big layers revert to R5 verbatim.
//  - NEW: int2+int3+int4+root fused into one kernel (tail_fused):
//    per (256-t tile, b) block: stage int1-out (128ch x 336 halo
//    window) in LDS, chain the three grouped convs LDS->LDS, then the
//    pointwise root. Waves statically own groups so A-fragments load
//    once per stage (L2-hot prep_A buffer). Replaces 4 launches + 3
//    HBM round-trips of the shrinking tail tensors.

#define T_LEN 4096
#define KK    15
#define TW    256            // output t-tile per block (16 tiles)
#define XS    288            // LDS X row stride (shorts); 2*XS % 128 == 64
#define SCP   264            // s_c row stride (shorts)

typedef __attribute__((ext_vector_type(8))) short    short8;
typedef __attribute__((ext_vector_type(4))) short    short4_t;
typedef __attribute__((ext_vector_type(4))) float    f32x4;
typedef __attribute__((ext_vector_type(2))) unsigned uint2_t;

static __device__ __forceinline__ short f2bf(float f) {
    union { __hip_bfloat16 b; short s; } u; u.b = __float2bfloat16(f); return u.s;
}
static __device__ __forceinline__ float bf2f(short s) {
    union { unsigned u; float f; } u; u.u = ((unsigned)(unsigned short)s) << 16; return u.f;
}

#define MODE_F32   0
#define MODE_BF16  1
#define MODE_SPLIT 2

// ---- Aprep layout: per layer, [g][j][lane][8] bf16, A[m=lane&15][kap] ----
// kap = j*32 + (lane>>4)*8 + e ; A[m][ic*16+kp] = W[g*8+(m&7)][ic][kp-(m>>3)]
#define AP_LEAF  0
#define AP_INT0  327680   // + 64*16*320
#define AP_BR    458752   // + 32*16*256
#define AP_INT1  589824
#define AP_INT2  655360
#define AP_INT3  688128
#define AP_INT4  704512
#define AP_TOTAL 712704

__global__ __launch_bounds__(256) void prep_A(
    const float* __restrict__ W0, const float* __restrict__ W1,
    const float* __restrict__ W2, const float* __restrict__ W3,
    const float* __restrict__ W4, const float* __restrict__ W5,
    const float* __restrict__ W6, short* __restrict__ Ap)
{
    const int idx = blockIdx.x * 256 + threadIdx.x;
    if (idx >= AP_TOTAL) return;
    const float* W; int ipg, base;
    if      (idx < AP_INT0) { W = W0; ipg = 20; base = AP_LEAF; }
    else if (idx < AP_BR)   { W = W1; ipg = 16; base = AP_INT0; }
    else if (idx < AP_INT1) { W = W2; ipg = 16; base = AP_BR;   }
    else if (idx < AP_INT2) { W = W3; ipg = 16; base = AP_INT1; }
    else if (idx < AP_INT3) { W = W4; ipg = 16; base = AP_INT2; }
    else if (idx < AP_INT4) { W = W5; ipg = 16; base = AP_INT3; }
    else                    { W = W6; ipg = 16; base = AP_INT4; }
    const int local = idx - base;
    const int e    = local & 7;
    const int fl   = local >> 3;
    const int lane = fl & 63;
    const int fj   = fl >> 6;           // g*NM + j
    int g, j;
    if (ipg == 20) { g = fj / 10; j = fj - g * 10; }
    else           { g = fj >> 3; j = fj & 7; }
    const int m   = lane & 15;
    const int kap = j * 32 + (lane >> 4) * 8 + e;
    const int ic  = kap >> 4, kp = kap & 15;
    const int k   = kp - (m >> 3);
    float v = 0.f;
    if (k >= 0 && k < KK)
        v = W[((size_t)(g * 8 + (m & 7)) * ipg + ic) * KK + k];
    Ap[idx] = f2bf(v);
}

// MODE_F32  : inA fp32, ch = g*IPG + r            (leaf; reads x)
// MODE_BF16 : inA bf16, ch = g*IPG + r            (int layers)
// MODE_SPLIT: r<8 from inA bf16 (ch=g*8+r), r>=8 from inX fp32
template <int IPG, int MODE>
__global__ __launch_bounds__(256) void gconv_mfma(
    const void*  __restrict__ inA_, int cinA,
    const float* __restrict__ inX,  int cinX, int xbase,
    const short* __restrict__ Ap,      // layer base pre-added
    const float* __restrict__ bias,
    short* __restrict__ out, int Cout)
{
    constexpr int KD = IPG * 16;   // padded K dim (320 or 256)
    constexpr int NM = KD / 32;    // MFMAs per output tile (10 or 8)

    __shared__ __align__(16) short s_x[IPG * XS];
    __shared__ __align__(16) short s_a[16 * KD];
    __shared__ __align__(16) short s_c[8 * SCP];

    const int tile = blockIdx.x, g = blockIdx.y, b = blockIdx.z;
    const int tid  = threadIdx.x;
    const int t_base = tile * TW - 8;   // aligned staging origin (LDS p=0 <-> t0-7)

    // ---- A: straight vectorized copy of precomputed fragments ----
    {
        const short* Ag = Ap + (size_t)g * (16 * KD);
        for (int i = tid; i < 2 * KD; i += 256)
            *(short8*)&s_a[i * 8] = *(const short8*)&Ag[i * 8];
    }

    // ---- X staging, vectorized; LDS value p <-> global t0-7+p ----
    if constexpr (MODE == MODE_BF16) {
        for (int v = tid; v < IPG * 34; v += 256) {
            const int r = v / 34, u = v - r * 34;
            const int gtb = t_base + 8 * u;          // multiple of 8: never partial OOB
            short8 sv = {0, 0, 0, 0, 0, 0, 0, 0};
            if (gtb >= 0 && gtb < T_LEN)
                sv = *(const short8*)((const short*)inA_ +
                      ((size_t)b * cinA + g * IPG + r) * T_LEN + gtb);
            short* row = s_x + r * XS;
            const int p0 = 8 * u;                    // element gtb+1 lands at p0
            if (u > 0) row[p0 - 1] = sv[0];
            uint2_t w;
            w.x = (unsigned short)sv[1] | ((unsigned)(unsigned short)sv[2] << 16);
            w.y = (unsigned short)sv[3] | ((unsigned)(unsigned short)sv[4] << 16);
            *(uint2_t*)(row + p0) = w;               // byte 576r+16u: 8B aligned
            *(unsigned*)(row + p0 + 4) =
                (unsigned short)sv[5] | ((unsigned)(unsigned short)sv[6] << 16);
            row[p0 + 6] = sv[7];
        }
    } else {
        for (int v = tid; v < IPG * 68; v += 256) {
            const int r = v / 68, u = v - r * 68;
            const int gtb = t_base + 4 * u;          // multiple of 4: never partial OOB
            short h0 = 0, h1 = 0, h2 = 0, h3 = 0;
            if (gtb >= 0 && gtb < T_LEN) {
                if constexpr (MODE == MODE_F32) {
                    f32x4 f = *(const f32x4*)((const float*)inA_ +
                          ((size_t)b * cinA + g * IPG + r) * T_LEN + gtb);
                    h0 = f2bf(f[0]); h1 = f2bf(f[1]); h2 = f2bf(f[2]); h3 = f2bf(f[3]);
                } else {               // MODE_SPLIT
                    if (r < 8) {
                        short4_t sv = *(const short4_t*)((const short*)inA_ +
                              ((size_t)b * cinA + g * 8 + r) * T_LEN + gtb);
                        h0 = sv[0]; h1 = sv[1]; h2 = sv[2]; h3 = sv[3];
                    } else {
                        f32x4 f = *(const f32x4*)(inX +
                              ((size_t)b * cinX + xbase + g * 8 + (r - 8)) * T_LEN + gtb);
                        h0 = f2bf(f[0]); h1 = f2bf(f[1]); h2 = f2bf(f[2]); h3 = f2bf(f[3]);
                    }
                }
            }
            short* row = s_x + r * XS;
            const int p0 = 4 * u;
            if (u > 0) row[p0 - 1] = h0;
            *(unsigned*)(row + p0) =                 // byte 576r+8u: 4B aligned
                (unsigned short)h1 | ((unsigned)(unsigned short)h2 << 16);
            row[p0 + 2] = h3;
        }
    }
    __syncthreads();

    const int l  = tid & 63;          // lane
    const int wv = tid >> 6;          // wave 0..3 (uniform)
    const int n  = l & 15, q = l >> 4;

    // fragment-major: wave reads 1KB contiguous -> conflict-free b128
    short8 fa[NM];
#pragma unroll
    for (int j = 0; j < NM; ++j)
        fa[j] = *(const short8*)&s_a[(j * 64 + l) * 8];

    float bv[4];
#pragma unroll
    for (int r = 0; r < 4; ++r) bv[r] = bias[g * 8 + ((q * 4 + r) & 7)];

    for (int c = 0; c < 2; ++c) {
        const int co = (wv * 2 + c) * 32;   // chunk t-offset within tile
        f32x4 acc = {bv[0], bv[1], bv[2], bv[3]};
#pragma unroll
        for (int j = 0; j < NM; ++j) {
            const int ic  = j * 2 + (q >> 1);
            const int idx = co + 2 * n + ((q & 1) * 8);    // even -> 4B aligned
            const unsigned* bp = (const unsigned*)&s_x[ic * XS + idx];
            union { unsigned u[4]; short8 v; } bb;
            bb.u[0] = bp[0]; bb.u[1] = bp[1]; bb.u[2] = bp[2]; bb.u[3] = bp[3];
            acc = __builtin_amdgcn_mfma_f32_16x16x32_bf16(fa[j], bb.v, acc, 0, 0, 0);
        }
#pragma unroll
        for (int r = 0; r < 4; ++r) {
            float vv = acc[r];
            vv = vv > 0.f ? vv : 0.01f * vv;
            const int m = q * 4 + r, oc = m & 7, s = m >> 3;
            s_c[oc * SCP + co + 2 * n + s] = f2bf(vv);
        }
    }
    __syncthreads();

    // ---- coalesced bf16 store: 8 rows x 256 cols, 16B per thread ----
    {
        const int oc = tid >> 5, col = (tid & 31) * 8;
        const short8 vvv = *(const short8*)&s_c[oc * SCP + col];
        *(short8*)(out + ((size_t)b * Cout + g * 8 + oc) * T_LEN + tile * TW + col) = vvv;
    }
}

// ================= fused tail: int2 + int3 + int4 + root =================
// Per (256-t tile, b) block, 512 threads (8 waves), 130KB LDS.
// s_in p=0 corresponds to local t = tstart-7 for each stage; B base
// p = 32c + 2n + 8(q&1) is even (4B-aligned) by construction.
__device__ __forceinline__ void tail_stage(
    const short* __restrict__ s_in, int sin_stride,
    short*       __restrict__ s_out, int sout_stride,
    const short* __restrict__ ApL, const float* __restrict__ bias,
    int g, int cbeg, int cend, int tstart, int poff, int t0, int l)
{
    const int n = l & 15, q = l >> 4;
    short8 fa[8];
    const short* Ag = ApL + (size_t)g * 4096;   // 16*256 shorts per group
#pragma unroll
    for (int j = 0; j < 8; ++j)
        fa[j] = *(const short8*)&Ag[(j * 64 + l) * 8];
    float bv[4];
#pragma unroll
    for (int r = 0; r < 4; ++r) bv[r] = bias[g * 8 + ((q * 4 + r) & 7)];

    for (int c = cbeg; c < cend; ++c) {
        const int co = c * 32;
        f32x4 acc = {bv[0], bv[1], bv[2], bv[3]};
#pragma unroll
        for (int j = 0; j < 8; ++j) {
            const int ic = j * 2 + (q >> 1);
            const unsigned* bp = (const unsigned*)
                &s_in[(g * 16 + ic) * sin_stride + co + 2 * n + 8 * (q & 1)];
            union { unsigned u[4]; short8 v; } bb;
            bb.u[0] = bp[0]; bb.u[1] = bp[1]; bb.u[2] = bp[2]; bb.u[3] = bp[3];
            acc = __builtin_amdgcn_mfma_f32_16x16x32_bf16(fa[j], bb.v, acc, 0, 0, 0);
        }
#pragma unroll
        for (int r = 0; r < 4; ++r) {
            const int m = q * 4 + r, oc = m & 7, s = m >> 3;
            const int t_loc = tstart + co + 2 * n + s;
            const int gt = t0 + t_loc;
            float vv = acc[r];
            vv = vv > 0.f ? vv : 0.01f * vv;
            // zero-mask outside [0,T): reproduces SAME zero padding
            const short val = (gt >= 0 && gt < T_LEN) ? f2bf(vv) : (short)0;
            const int p = t_loc + poff;
            if (p >= 0)
                s_out[(g * 8 + oc) * sout_stride + p] = val;
        }
    }
}

__global__ __launch_bounds__(512) void tail_fused(
    const short* __restrict__ h1,   // int1-out, 128 ch bf16
    const short* __restrict__ Ap,   // prep_A base
    const float* __restrict__ b2, const float* __restrict__ b3,
    const float* __restrict__ b4,
    const float* __restrict__ Wr, const float* __restrict__ br_,
    float* __restrict__ out)
{
    // 65024 shorts = 130048 B:
    //  s_h1: [0, 44032)        128 x 344   (int1-out, p=0 <-> t0-23)
    //  s_h3: [0, 9472)         32 x 296    (alias; s_h1 dead by then)
    //  s_h4: [10240, 14464)    16 x 264    (disjoint from s_h3)
    //  s_h2: [44032, 65024)    64 x 328
    __shared__ __align__(16) short s_mem[65024];
    short* s_h1 = s_mem;
    short* s_h3 = s_mem;
    short* s_h4 = s_mem + 10240;
    short* s_h2 = s_mem + 44032;

    const int tile = blockIdx.x, b = blockIdx.z;
    const int tid  = threadIdx.x;
    const int t0   = tile * 256;
    const int l = tid & 63, wv = tid >> 6;

    // ---- stage int1-out window [t0-23, t0+311): p = 8u + e - 1 ----
    for (int v = tid; v < 128 * 43; v += 512) {
        const int r = v / 43, u = v - r * 43;
        const int gt = t0 - 24 + 8 * u;
        short8 sv = {0, 0, 0, 0, 0, 0, 0, 0};
        if (gt >= 0 && gt < T_LEN)
            sv = *(const short8*)&h1[((size_t)b * 128 + r) * T_LEN + gt];
        short* row = s_h1 + r * 344;
        const int p0 = 8 * u;
        if (u > 0) row[p0 - 1] = sv[0];
        uint2_t w;
        w.x = (unsigned short)sv[1] | ((unsigned)(unsigned short)sv[2] << 16);
        w.y = (unsigned short)sv[3] | ((unsigned)(unsigned short)sv[4] << 16);
        *(uint2_t*)(row + p0) = w;               // 8B aligned
        *(unsigned*)(row + p0 + 4) =
            (unsigned short)sv[5] | ((unsigned)(unsigned short)sv[6] << 16);
        row[p0 + 6] = sv[7];
    }
    __syncthreads();

    // int2: out [-16,304) (10 chunks), 8 groups; wave = group
    tail_stage(s_h1, 344, s_h2, 328, Ap + AP_INT2, b2,
               wv, 0, 10, -16, 15, t0, l);
    __syncthreads();
    // int3: out [-8,280) (9 chunks), 4 groups; wave pairs split chunks
    tail_stage(s_h2, 328, s_h3, 296, Ap + AP_INT3, b3,
               wv >> 1, (wv & 1) * 5, (wv & 1) ? 9 : 5, -8, 7, t0, l);
    __syncthreads();
    // int4: out [0,256) (8 chunks), 2 groups; wave quads split chunks
    tail_stage(s_h3, 296, s_h4, 264, Ap + AP_INT4, b4,
               wv >> 2, (wv & 3) * 2, (wv & 3) * 2 + 2, 0, 0, t0, l);
    __syncthreads();

    // ---- root: pointwise 16ch -> fp32 ----
    if (tid < 256) {
        float acc = br_[0];
#pragma unroll
        for (int ic = 0; ic < 16; ++ic)
            acc += Wr[ic] * bf2f(s_h4[ic * 264 + tid]);
        out[(size_t)b * T_LEN + t0 + tid] = acc;
    }
}

extern "C" void kernel_launch(void* const* d_in, const int* in_sizes, int n_in,
                              void* d_out, int out_size, void* d_ws, size_t ws_size,
                              hipStream_t stream)
{
    const float* x      = (const float*)d_in[0];
    const float* W_leaf = (const float*)d_in[1];
    const float* b_leaf = (const float*)d_in[2];
    const float* W_int0 = (const float*)d_in[3];
    const float* b_int0 = (const float*)d_in[4];
    const float* W_br   = (const float*)d_in[5];
    const float* b_br   = (const float*)d_in[6];
    const float* W_int1 = (const float*)d_in[7];
    const float* b_int1 = (const float*)d_in[8];
    const float* W_int2 = (const float*)d_in[9];
    const float* b_int2 = (const float*)d_in[10];
    const float* W_int3 = (const float*)d_in[11];
    const float* b_int3 = (const float*)d_in[12];
    const float* W_int4 = (const float*)d_in[13];
    const float* b_int4 = (const float*)d_in[14];
    const float* W_root = (const float*)d_in[15];
    const float* b_root = (const float*)d_in[16];

    // ws: bufA (67.1MB) | bufB (33.6MB) | Aprep (1.43MB)
    short* bufA = (short*)d_ws;
    short* bufB = bufA + (size_t)16 * 512 * 4096;
    short* Ap   = bufB + (size_t)16 * 256 * 4096;

    const int tiles = T_LEN / TW;  // 16
    const dim3 blk(256);

    prep_A<<<dim3(AP_TOTAL / 256), blk, 0, stream>>>(
        W_leaf, W_int0, W_br, W_int1, W_int2, W_int3, W_int4, Ap);

    // leaf: x fp32 (ch=g*20+r) -> bufA (512 ch bf16)
    gconv_mfma<20, MODE_F32><<<dim3(tiles, 64, 16), blk, 0, stream>>>(
        x, 1536, nullptr, 0, 0, Ap + AP_LEAF, b_leaf, bufA, 512);
    // int0: bufA (512) -> bufB (256)
    gconv_mfma<16, MODE_BF16><<<dim3(tiles, 32, 16), blk, 0, stream>>>(
        bufA, 512, nullptr, 0, 0, Ap + AP_INT0, b_int0, bufB, 256);
    // br: [bufB (256) | x ch1280..1535 fp32] -> bufA (256)
    gconv_mfma<16, MODE_SPLIT><<<dim3(tiles, 32, 16), blk, 0, stream>>>(
        bufB, 256, x, 1536, 1280, Ap + AP_BR, b_br, bufA, 256);
    // int1: bufA (256) -> bufB (128)
    gconv_mfma<16, MODE_BF16><<<dim3(tiles, 16, 16), blk, 0, stream>>>(
        bufA, 256, nullptr, 0, 0, Ap + AP_INT1, b_int1, bufB, 128);
    // fused tail: bufB (128 ch) -> d_out fp32
    tail_fused<<<dim3(16, 1, 16), dim3(512), 0, stream>>>(
        bufB, Ap, b_int2, b_int3, b_int4, W_root, b_root, (float*)d_out);
}